// Round 10
// baseline (615.691 us; speedup 1.0000x reference)
//
#include <hip/hip_runtime.h>
#include <hip/hip_bf16.h>

typedef unsigned int  uint_t;
typedef unsigned short ushort_t;

#define NN 50000
#define NE 800000
#define NBLK 196   // cdiv(NN,256)

static inline int cdiv(long long a, long long b) { return (int)((a + b - 1) / b); }

// ---- bf16 pair helpers (element j at low 16 bits) ----
__device__ inline float bflo(uint_t u) { return __uint_as_float(u << 16); }
__device__ inline float bfhi(uint_t u) { return __uint_as_float(u & 0xffff0000u); }
__device__ inline uint_t packbf(float x, float y) {  // RNE
    uint_t xu = __float_as_uint(x), yu = __float_as_uint(y);
    xu += 0x7fffu + ((xu >> 16) & 1u);
    yu += 0x7fffu + ((yu >> 16) & 1u);
    return (xu >> 16) | (yu & 0xffff0000u);
}
__device__ inline ushort_t packbf1(float x) {
    uint_t xu = __float_as_uint(x);
    xu += 0x7fffu + ((xu >> 16) & 1u);
    return (ushort_t)(xu >> 16);
}

// ---------------- CSR build ----------------

__global__ void k_prep(int* __restrict__ deg, float* __restrict__ bnacc) {
    int i = blockIdx.x * blockDim.x + threadIdx.x;
    if (i < NN) deg[i] = 0;
    if (i < 768) bnacc[i] = 0.0f;
}

__global__ void k_hist(const int* __restrict__ dst, int* __restrict__ deg) {
    int e = blockIdx.x * blockDim.x + threadIdx.x;
    if (e < NE) {
        int d = dst[e];
        if ((unsigned)d < NN) atomicAdd(&deg[d], 1);
    }
}

__global__ void k_bsum(const int* __restrict__ deg, int* __restrict__ bsum) {
    __shared__ int l[256];
    int tid = threadIdx.x;
    int i = blockIdx.x * 256 + tid;
    l[tid] = (i < NN) ? deg[i] : 0;
    __syncthreads();
    for (int o = 128; o > 0; o >>= 1) {
        if (tid < o) l[tid] += l[tid + o];
        __syncthreads();
    }
    if (tid == 0) bsum[blockIdx.x] = l[0];
}

__global__ void k_bscan(const int* __restrict__ bsum, int* __restrict__ boff,
                        int* __restrict__ row_ptr) {
    __shared__ int l[256];
    int tid = threadIdx.x;
    int v = (tid < NBLK) ? bsum[tid] : 0;
    l[tid] = v;
    __syncthreads();
    for (int o = 1; o < 256; o <<= 1) {
        int t = (tid >= o) ? l[tid - o] : 0;
        __syncthreads();
        l[tid] += t;
        __syncthreads();
    }
    boff[tid] = l[tid] - v;
    if (tid == 255) row_ptr[NN] = l[255];
}

__global__ void k_rowptr(const int* __restrict__ deg, const int* __restrict__ boff,
                         int* __restrict__ row_ptr, int* __restrict__ cursor,
                         float* __restrict__ dis) {
    __shared__ int l[256];
    int tid = threadIdx.x;
    int i = blockIdx.x * 256 + tid;
    int v = (i < NN) ? deg[i] : 0;
    l[tid] = v;
    __syncthreads();
    for (int o = 1; o < 256; o <<= 1) {
        int t = (tid >= o) ? l[tid - o] : 0;
        __syncthreads();
        l[tid] += t;
        __syncthreads();
    }
    if (i < NN) {
        int excl = boff[blockIdx.x] + l[tid] - v;
        row_ptr[i] = excl;
        cursor[i] = excl;
        dis[i] = rsqrtf((float)(v + 1));  // +1 self-loop
    }
}

// packed (col, wgt) fill: ONE 8B random store per edge
__global__ void k_fill(const int* __restrict__ src, const int* __restrict__ dst,
                       const float* __restrict__ dis,
                       int* __restrict__ cursor, int2* __restrict__ cw) {
    int e = blockIdx.x * blockDim.x + threadIdx.x;
    if (e < NE) {
        int s = src[e], d = dst[e];
        if ((unsigned)s < NN && (unsigned)d < NN) {
            int p = atomicAdd(&cursor[d], 1);
            cw[p] = make_int2(s, __float_as_int(dis[s] * dis[d]));
        }
    }
}

// ---------------- generic weight fold/pad (runtime dims) ----------------
struct FoldJob {
    const float* W; const float* b;
    const float* bnacc; const float* g; const float* be;
    float* Wp; float* bf;
    int FI, FO, in_bn, out_b;
};
struct FoldJobs { FoldJob j[4]; };

__global__ void k_fold(FoldJobs jobs) {
    FoldJob J = jobs.j[blockIdx.x];
    const int FI = J.FI, FO = J.FO;
    const int NT = (FO + 15) / 16, FOP = 16 * NT;
    __shared__ float scl[96], shl[96];
    int tid = threadIdx.x;
    if (J.in_bn) {
        if (tid < FI) {
            const float inv_n = 1.0f / NN;
            float mu = J.bnacc[tid] * inv_n;
            float va = J.bnacc[96 + tid] * inv_n - mu * mu;
            float r  = rsqrtf(va + 1e-5f);
            float sc = J.g[tid] * r;
            scl[tid] = sc;
            shl[tid] = J.be[tid] - mu * sc;
        }
        __syncthreads();
    }
    for (int idx = tid; idx < FI * FOP; idx += 256) {
        int k = idx / FOP, j = idx - k * FOP;
        float w = (j < FO) ? J.W[k * FO + j] : 0.0f;
        if (J.in_bn) w *= scl[k];
        J.Wp[(k >> 1) * 2 * FOP + 2 * j + (k & 1)] = w;
    }
    if (tid < FOP) {
        float a = (J.out_b && tid < FO) ? J.b[tid] : 0.0f;
        if (J.in_bn && tid < FO) {
            for (int k = 0; k < FI; ++k) a = fmaf(shl[k], J.W[k * FO + tid], a);
        }
        J.bf[tid] = a;
    }
}

// ---------------- dense: H = in_tf(X) @ Wp + biasf ----------------
// bf16 rows padded to JW=4*ceil(FO/4) features; pad outputs are exact 0.
template<int FI, int FO, int IN_BN, int IN_F32, int OUT_F32, int OUT_BN>
__global__ __launch_bounds__(256)
void k_dense(const void* __restrict__ Xv, const float* __restrict__ Wp,
             const float* __restrict__ biasf, void* __restrict__ Hv,
             float* __restrict__ bnst) {
    constexpr int NT  = (FO + 15) / 16;
    constexpr int FOP = 16 * NT;
    constexpr int JW  = 4 * ((FO + 3) / 4);    // padded output width (features)
    constexpr int FIP = FI + 2;
    constexpr int KP  = FI / 2;
    constexpr int S2I = 2 * ((FI + 3) / 4);    // bf16 input row stride (uints)

    __shared__ __align__(16) float xs[64 * FIP];
    __shared__ float ls[96], lq[96];

    int tid = threadIdx.x;
    int node0 = blockIdx.x * 64;

    if (OUT_BN) {
        if (tid < 96) { ls[tid] = 0.0f; lq[tid] = 0.0f; }
    }

    // ---- stage X tile (coalesced) ----
    if (IN_F32) {
        for (int idx = tid; idx < 64 * FI; idx += 256) {
            int r = idx / FI, c = idx - r * FI;
            int n = node0 + r;
            float v = (n < NN) ? ((const float*)Xv)[(size_t)n * FI + c] : 0.0f;
            if (IN_BN) v = fmaxf(v, 0.0f);
            xs[r * FIP + c] = v;
        }
    } else {
        for (int idx = tid; idx < 64 * KP; idx += 256) {
            int r = idx / KP, c2 = idx - r * KP;
            int n = node0 + r;
            uint_t u = (n < NN) ? ((const uint_t*)Xv)[(size_t)n * S2I + c2] : 0u;
            float f0 = bflo(u), f1 = bfhi(u);
            if (IN_BN) { f0 = fmaxf(f0, 0.0f); f1 = fmaxf(f1, 0.0f); }
            xs[r * FIP + 2 * c2]     = f0;
            xs[r * FIP + 2 * c2 + 1] = f1;
        }
    }
    __syncthreads();

    int ng = tid >> 4;
    int cg = tid & 15;

    float acc[4][NT];
    #pragma unroll
    for (int i = 0; i < 4; ++i)
        #pragma unroll
        for (int t = 0; t < NT; ++t) acc[i][t] = biasf[cg + 16 * t];

    #pragma unroll 2
    for (int k = 0; k < FI; k += 2) {
        float2 xv[4];
        #pragma unroll
        for (int i = 0; i < 4; ++i)
            xv[i] = *(const float2*)&xs[(ng + 16 * i) * FIP + k];
        const float* wrow = &Wp[(k >> 1) * 2 * FOP];
        #pragma unroll
        for (int t = 0; t < NT; ++t) {
            float2 w = *(const float2*)&wrow[2 * (cg + 16 * t)];
            #pragma unroll
            for (int i = 0; i < 4; ++i)
                acc[i][t] = fmaf(xv[i].y, w.y, fmaf(xv[i].x, w.x, acc[i][t]));
        }
    }

    if (OUT_BN) {
        #pragma unroll
        for (int t = 0; t < NT; ++t) {
            int j = cg + 16 * t;
            if (j < FO) {
                float ps = 0.0f, pq = 0.0f;
                #pragma unroll
                for (int i = 0; i < 4; ++i) {
                    if (node0 + ng + 16 * i < NN) {
                        float r = fmaxf(acc[i][t], 0.0f);
                        ps += r; pq += r * r;
                    }
                }
                atomicAdd(&ls[j], ps);
                atomicAdd(&lq[j], pq);
            }
        }
        __syncthreads();
        if (tid < FO) {
            atomicAdd(&bnst[tid], ls[tid]);
            atomicAdd(&bnst[96 + tid], lq[tid]);
        }
    }

    // ---- store (coalesced 16-lane segments); pads are exact zeros ----
    #pragma unroll
    for (int i = 0; i < 4; ++i) {
        int n = node0 + ng + 16 * i;
        if (n < NN) {
            #pragma unroll
            for (int t = 0; t < NT; ++t) {
                int j = cg + 16 * t;
                if (OUT_F32) {
                    if (j < FO) ((float*)Hv)[(size_t)n * FO + j] = acc[i][t];
                } else {
                    if (j < JW) ((ushort_t*)Hv)[(size_t)n * JW + j] = packbf1(acc[i][t]);
                }
            }
        }
    }
}

// ---------------- CSR gather: 4 features/thread, uint2 row loads ----------------
// grid = F4 * NBLK blocks of 256 -> one (node, 4-feature) slot per thread.
template<int FO, int IN_BN, int OUT_BIAS, int OUT_BN>
__global__ __launch_bounds__(256)
void k_gather(const uint_t* __restrict__ h, const int* __restrict__ row_ptr,
              const int2* __restrict__ cw, const float* __restrict__ dis,
              const float* __restrict__ bnacc, const float* __restrict__ g,
              const float* __restrict__ be,
              const float* __restrict__ b, uint_t* __restrict__ A,
              float* __restrict__ bnacc_out) {
    constexpr int F4 = (FO + 3) / 4;
    constexpr int S2 = 2 * F4;           // row stride in uints
    __shared__ float ls[96], lq[96];
    int tid = threadIdx.x;
    if (OUT_BN) {
        if (tid < 96) { ls[tid] = 0.0f; lq[tid] = 0.0f; }
        __syncthreads();
    }

    int t = blockIdx.x * blockDim.x + tid;
    int i  = t / F4;
    int j4 = t - i * F4;
    int j  = 4 * j4;
    bool valid = i < NN;

    float sc[4], sh[4];
    if (IN_BN) {
        const float inv_n = 1.0f / NN;
        #pragma unroll
        for (int q = 0; q < 4; ++q) {
            int jq = j + q;
            if (jq < FO) {
                float mu = bnacc[jq] * inv_n;
                float va = bnacc[96 + jq] * inv_n - mu * mu;
                float r  = rsqrtf(va + 1e-5f);
                sc[q] = g[jq] * r; sh[q] = be[jq] - mu * sc[q];
            } else { sc[q] = 0.0f; sh[q] = 0.0f; }
        }
    }

    float a0 = 0.0f, a1 = 0.0f, a2 = 0.0f, a3 = 0.0f;

    if (valid) {
        const uint_t* hq = h + 2 * j4;   // column quad within rows
        float di = dis[i];

        // self-loop (+ bias)
        uint2 su = *(const uint2*)(hq + (size_t)i * S2);
        float f0 = bflo(su.x), f1 = bfhi(su.x), f2 = bflo(su.y), f3 = bfhi(su.y);
        if (IN_BN) {
            f0 = fmaxf(f0, 0.0f) * sc[0] + sh[0]; f1 = fmaxf(f1, 0.0f) * sc[1] + sh[1];
            f2 = fmaxf(f2, 0.0f) * sc[2] + sh[2]; f3 = fmaxf(f3, 0.0f) * sc[3] + sh[3];
        }
        float dd = di * di;
        a0 = f0 * dd; a1 = f1 * dd; a2 = f2 * dd; a3 = f3 * dd;
        if (OUT_BIAS) {
            #pragma unroll
            for (int q = 0; q < 4; ++q) {
                int jq = j + q;
                float bv = (jq < FO) ? b[jq] : 0.0f;
                if (q == 0) a0 += bv; else if (q == 1) a1 += bv;
                else if (q == 2) a2 += bv; else a3 += bv;
            }
        }

        int k = row_ptr[i], end = row_ptr[i + 1];
        for (; k + 8 <= end; k += 8) {
            int2  c[8]; uint2 u[8];
            #pragma unroll
            for (int q = 0; q < 8; ++q) c[q] = cw[k + q];
            #pragma unroll
            for (int q = 0; q < 8; ++q)
                u[q] = *(const uint2*)(hq + (size_t)c[q].x * S2);
            #pragma unroll
            for (int q = 0; q < 8; ++q) {
                float w = __int_as_float(c[q].y);
                float t0 = bflo(u[q].x), t1 = bfhi(u[q].x);
                float t2 = bflo(u[q].y), t3 = bfhi(u[q].y);
                if (IN_BN) {
                    t0 = fmaxf(t0, 0.0f) * sc[0] + sh[0]; t1 = fmaxf(t1, 0.0f) * sc[1] + sh[1];
                    t2 = fmaxf(t2, 0.0f) * sc[2] + sh[2]; t3 = fmaxf(t3, 0.0f) * sc[3] + sh[3];
                }
                a0 = fmaf(t0, w, a0); a1 = fmaf(t1, w, a1);
                a2 = fmaf(t2, w, a2); a3 = fmaf(t3, w, a3);
            }
        }
        for (; k < end; ++k) {
            int2 c = cw[k];
            float w = __int_as_float(c.y);
            uint2 u = *(const uint2*)(hq + (size_t)c.x * S2);
            float t0 = bflo(u.x), t1 = bfhi(u.x), t2 = bflo(u.y), t3 = bfhi(u.y);
            if (IN_BN) {
                t0 = fmaxf(t0, 0.0f) * sc[0] + sh[0]; t1 = fmaxf(t1, 0.0f) * sc[1] + sh[1];
                t2 = fmaxf(t2, 0.0f) * sc[2] + sh[2]; t3 = fmaxf(t3, 0.0f) * sc[3] + sh[3];
            }
            a0 = fmaf(t0, w, a0); a1 = fmaf(t1, w, a1);
            a2 = fmaf(t2, w, a2); a3 = fmaf(t3, w, a3);
        }

        *(uint2*)(A + (size_t)i * S2 + 2 * j4) =
            make_uint2(packbf(a0, a1), packbf(a2, a3));
    }

    if (OUT_BN) {
        if (valid) {
            float r0 = fmaxf(a0, 0.0f), r1 = fmaxf(a1, 0.0f);
            float r2 = fmaxf(a2, 0.0f), r3 = fmaxf(a3, 0.0f);
            if (j     < FO) { atomicAdd(&ls[j],     r0); atomicAdd(&lq[j],     r0 * r0); }
            if (j + 1 < FO) { atomicAdd(&ls[j + 1], r1); atomicAdd(&lq[j + 1], r1 * r1); }
            if (j + 2 < FO) { atomicAdd(&ls[j + 2], r2); atomicAdd(&lq[j + 2], r2 * r2); }
            if (j + 3 < FO) { atomicAdd(&ls[j + 3], r3); atomicAdd(&lq[j + 3], r3 * r3); }
        }
        __syncthreads();
        if (tid < FO) {
            atomicAdd(&bnacc_out[tid], ls[tid]);
            atomicAdd(&bnacc_out[96 + tid], lq[tid]);
        }
    }
}

extern "C" void kernel_launch(void* const* d_in, const int* in_sizes, int n_in,
                              void* d_out, int out_size, void* d_ws, size_t ws_size,
                              hipStream_t stream) {
    const float* x = (const float*)d_in[0];
    const int* ei = (const int*)d_in[1];
    const int* src = ei;
    const int* dst = ei + NE;
    const float* W1 = (const float*)d_in[2];  const float* b1 = (const float*)d_in[3];
    const float* W2 = (const float*)d_in[4];  const float* b2 = (const float*)d_in[5];
    const float* W3 = (const float*)d_in[6];  const float* b3 = (const float*)d_in[7];
    const float* W4 = (const float*)d_in[8];  const float* b4 = (const float*)d_in[9];
    const float* W5 = (const float*)d_in[10]; const float* b5 = (const float*)d_in[11];
    const float* W6 = (const float*)d_in[12]; const float* b6 = (const float*)d_in[13];
    const float* g1 = (const float*)d_in[14]; const float* be1 = (const float*)d_in[15];
    const float* g2 = (const float*)d_in[16]; const float* be2 = (const float*)d_in[17];
    const float* g3 = (const float*)d_in[18]; const float* be3 = (const float*)d_in[19];
    const float* g4 = (const float*)d_in[20]; const float* be4 = (const float*)d_in[21];

    // workspace (~28 MB), cw first for 8B alignment; row_ptr padded to even count
    int2* cw      = (int2*)d_ws;                 // NE
    float* dis    = (float*)(cw + NE);           // NN
    float* bnacc  = dis + NN;                    // 768
    float* Wp     = bnacc + 768;                 // 6*7040
    float* biasf  = Wp + 6 * 7040;               // 6*96
    int* deg      = (int*)(biasf + 6 * 96);      // NN
    int* row_ptr  = deg + NN;                    // NN+2 (even, keeps 8B align below)
    int* cursor   = row_ptr + NN + 2;            // NN
    int* bsum     = cursor + NN;                 // 256
    int* boff     = bsum + 256;                  // 256
    uint_t* hB    = (uint_t*)(boff + 256);       // NN*36 (max padded row)
    uint_t* aB    = hB + (size_t)NN * 36;        // NN*36
    float* out    = (float*)d_out;

    const int NB = 256;
    const int DGRID = cdiv(NN, 64);
    float* bn0 = bnacc;        // L1 stats (g1,be1)
    float* bn1 = bnacc + 192;  // L2 stats (g2,be2)
    float* bn2 = bnacc + 384;  // L4 stats (g3,be3)
    float* bn3 = bnacc + 576;  // L5 stats (g4,be4)
    float* WpL[6]; float* bfL[6];
    for (int i = 0; i < 6; ++i) { WpL[i] = Wp + i * 7040; bfL[i] = biasf + i * 96; }

    // ---- CSR + normalization build ----
    k_prep<<<cdiv(NN, NB), NB, 0, stream>>>(deg, bnacc);
    k_hist<<<cdiv(NE, NB), NB, 0, stream>>>(dst, deg);
    k_bsum<<<NBLK, 256, 0, stream>>>(deg, bsum);
    k_bscan<<<1, 256, 0, stream>>>(bsum, boff, row_ptr);
    k_rowptr<<<NBLK, 256, 0, stream>>>(deg, boff, row_ptr, cursor, dis);
    k_fill<<<cdiv(NE, NB), NB, 0, stream>>>(src, dst, dis, cursor, cw);

    // ---- fold BN-independent layers (L1,L4,L5,L6) in one launch ----
    {
        FoldJobs js;
        js.j[0] = {W1, nullptr, nullptr, nullptr, nullptr, WpL[0], bfL[0], 88, 70, 0, 0};
        js.j[1] = {W4, b4,      nullptr, nullptr, nullptr, WpL[3], bfL[3], 50, 60, 0, 1};
        js.j[2] = {W5, b5,      nullptr, nullptr, nullptr, WpL[4], bfL[4], 60, 70, 0, 1};
        js.j[3] = {W6, b6,      nullptr, nullptr, nullptr, WpL[5], bfL[5], 70, 88, 0, 1};
        k_fold<<<4, 256, 0, stream>>>(js);
    }

    // ---- L1: dense x(88,f32)->hB(70); gather+bn0: hB -> aB + b1 ----
    k_dense<88, 70, 0, 1, 0, 0><<<DGRID, 256, 0, stream>>>(x, WpL[0], bfL[0], hB, nullptr);
    k_gather<70, 0, 1, 1><<<18 * NBLK, NB, 0, stream>>>(
        hB, row_ptr, cw, dis, nullptr, nullptr, nullptr, b1, aB, bn0);

    // ---- L2: fold(bn0); dense relu(aB)(70)->hB(60); gather+bn1 -> aB + b2 ----
    {
        FoldJobs js;
        js.j[0] = {W2, nullptr, bn0, g1, be1, WpL[1], bfL[1], 70, 60, 1, 0};
        k_fold<<<1, 256, 0, stream>>>(js);
    }
    k_dense<70, 60, 1, 0, 0, 0><<<DGRID, 256, 0, stream>>>(aB, WpL[1], bfL[1], hB, nullptr);
    k_gather<60, 0, 1, 1><<<15 * NBLK, NB, 0, stream>>>(
        hB, row_ptr, cw, dis, nullptr, nullptr, nullptr, b2, aB, bn1);

    // ---- L3: fold(bn1); dense relu(aB)(60)->hB(50); gather -> aB + b3 ----
    {
        FoldJobs js;
        js.j[0] = {W3, nullptr, bn1, g2, be2, WpL[2], bfL[2], 60, 50, 1, 0};
        k_fold<<<1, 256, 0, stream>>>(js);
    }
    k_dense<60, 50, 1, 0, 0, 0><<<DGRID, 256, 0, stream>>>(aB, WpL[2], bfL[2], hB, nullptr);
    k_gather<50, 0, 1, 0><<<13 * NBLK, NB, 0, stream>>>(
        hB, row_ptr, cw, dis, nullptr, nullptr, nullptr, b3, aB, nullptr);

    // ---- L4 (aggregate-first): gather aB(A3)->hB(50); dense+bn2: hB->aB(60)+b4 ----
    k_gather<50, 0, 0, 0><<<13 * NBLK, NB, 0, stream>>>(
        aB, row_ptr, cw, dis, nullptr, nullptr, nullptr, nullptr, hB, nullptr);
    k_dense<50, 60, 0, 0, 0, 1><<<DGRID, 256, 0, stream>>>(hB, WpL[3], bfL[3], aB, bn2);

    // ---- L5: gather bn2(relu(aB))->hB(60); dense+bn3: hB->aB(70)+b5 ----
    k_gather<60, 1, 0, 0><<<15 * NBLK, NB, 0, stream>>>(
        aB, row_ptr, cw, dis, bn2, g3, be3, nullptr, hB, nullptr);
    k_dense<60, 70, 0, 0, 0, 1><<<DGRID, 256, 0, stream>>>(hB, WpL[4], bfL[4], aB, bn3);

    // ---- L6: gather bn3(relu(aB))->hB(70); dense: hB->out(88,f32)+b6 ----
    k_gather<70, 1, 0, 0><<<18 * NBLK, NB, 0, stream>>>(
        aB, row_ptr, cw, dis, bn3, g4, be4, nullptr, hB, nullptr);
    k_dense<70, 88, 0, 0, 1, 0><<<DGRID, 256, 0, stream>>>(hB, WpL[5], bfL[5], out, nullptr);
}

// Round 11
// 603.555 us; speedup vs baseline: 1.0201x; 1.0201x over previous
//
#include <hip/hip_runtime.h>
#include <hip/hip_bf16.h>

typedef unsigned int  uint_t;
typedef unsigned short ushort_t;

#define NN 50000
#define NE 800000
#define NBLK 196   // cdiv(NN,256)

static inline int cdiv(long long a, long long b) { return (int)((a + b - 1) / b); }

// ---- bf16 pair helpers (element j at low 16 bits) ----
__device__ inline float bflo(uint_t u) { return __uint_as_float(u << 16); }
__device__ inline float bfhi(uint_t u) { return __uint_as_float(u & 0xffff0000u); }
__device__ inline uint_t packbf(float x, float y) {  // RNE
    uint_t xu = __float_as_uint(x), yu = __float_as_uint(y);
    xu += 0x7fffu + ((xu >> 16) & 1u);
    yu += 0x7fffu + ((yu >> 16) & 1u);
    return (xu >> 16) | (yu & 0xffff0000u);
}
__device__ inline ushort_t packbf1(float x) {
    uint_t xu = __float_as_uint(x);
    xu += 0x7fffu + ((xu >> 16) & 1u);
    return (ushort_t)(xu >> 16);
}

// ---------------- CSR build ----------------

__global__ void k_prep(int* __restrict__ deg, float* __restrict__ bnacc) {
    int i = blockIdx.x * blockDim.x + threadIdx.x;
    if (i < NN) deg[i] = 0;
    if (i < 768) bnacc[i] = 0.0f;
}

__global__ void k_hist(const int* __restrict__ dst, int* __restrict__ deg) {
    int e = blockIdx.x * blockDim.x + threadIdx.x;
    if (e < NE) {
        int d = dst[e];
        if ((unsigned)d < NN) atomicAdd(&deg[d], 1);
    }
}

__global__ void k_bsum(const int* __restrict__ deg, int* __restrict__ bsum) {
    __shared__ int l[256];
    int tid = threadIdx.x;
    int i = blockIdx.x * 256 + tid;
    l[tid] = (i < NN) ? deg[i] : 0;
    __syncthreads();
    for (int o = 128; o > 0; o >>= 1) {
        if (tid < o) l[tid] += l[tid + o];
        __syncthreads();
    }
    if (tid == 0) bsum[blockIdx.x] = l[0];
}

__global__ void k_bscan(const int* __restrict__ bsum, int* __restrict__ boff,
                        int* __restrict__ row_ptr) {
    __shared__ int l[256];
    int tid = threadIdx.x;
    int v = (tid < NBLK) ? bsum[tid] : 0;
    l[tid] = v;
    __syncthreads();
    for (int o = 1; o < 256; o <<= 1) {
        int t = (tid >= o) ? l[tid - o] : 0;
        __syncthreads();
        l[tid] += t;
        __syncthreads();
    }
    boff[tid] = l[tid] - v;
    if (tid == 255) row_ptr[NN] = l[255];
}

__global__ void k_rowptr(const int* __restrict__ deg, const int* __restrict__ boff,
                         int* __restrict__ row_ptr, int* __restrict__ cursor,
                         float* __restrict__ dis) {
    __shared__ int l[256];
    int tid = threadIdx.x;
    int i = blockIdx.x * 256 + tid;
    int v = (i < NN) ? deg[i] : 0;
    l[tid] = v;
    __syncthreads();
    for (int o = 1; o < 256; o <<= 1) {
        int t = (tid >= o) ? l[tid - o] : 0;
        __syncthreads();
        l[tid] += t;
        __syncthreads();
    }
    if (i < NN) {
        int excl = boff[blockIdx.x] + l[tid] - v;
        row_ptr[i] = excl;
        cursor[i] = excl;
        dis[i] = rsqrtf((float)(v + 1));  // +1 self-loop
    }
}

// packed (col, wgt) fill: ONE 8B random store per edge
__global__ void k_fill(const int* __restrict__ src, const int* __restrict__ dst,
                       const float* __restrict__ dis,
                       int* __restrict__ cursor, int2* __restrict__ cw) {
    int e = blockIdx.x * blockDim.x + threadIdx.x;
    if (e < NE) {
        int s = src[e], d = dst[e];
        if ((unsigned)s < NN && (unsigned)d < NN) {
            int p = atomicAdd(&cursor[d], 1);
            cw[p] = make_int2(s, __float_as_int(dis[s] * dis[d]));
        }
    }
}

// ---------------- generic weight fold/pad (runtime dims) ----------------
struct FoldJob {
    const float* W; const float* b;
    const float* bnacc; const float* g; const float* be;
    float* Wp; float* bf;
    int FI, FO, in_bn, out_b;
};
struct FoldJobs { FoldJob j[4]; };

__global__ void k_fold(FoldJobs jobs) {
    FoldJob J = jobs.j[blockIdx.x];
    const int FI = J.FI, FO = J.FO;
    const int NT = (FO + 15) / 16, FOP = 16 * NT;
    __shared__ float scl[96], shl[96];
    int tid = threadIdx.x;
    if (J.in_bn) {
        if (tid < FI) {
            const float inv_n = 1.0f / NN;
            float mu = J.bnacc[tid] * inv_n;
            float va = J.bnacc[96 + tid] * inv_n - mu * mu;
            float r  = rsqrtf(va + 1e-5f);
            float sc = J.g[tid] * r;
            scl[tid] = sc;
            shl[tid] = J.be[tid] - mu * sc;
        }
        __syncthreads();
    }
    for (int idx = tid; idx < FI * FOP; idx += 256) {
        int k = idx / FOP, j = idx - k * FOP;
        float w = (j < FO) ? J.W[k * FO + j] : 0.0f;
        if (J.in_bn) w *= scl[k];
        J.Wp[(k >> 1) * 2 * FOP + 2 * j + (k & 1)] = w;
    }
    if (tid < FOP) {
        float a = (J.out_b && tid < FO) ? J.b[tid] : 0.0f;
        if (J.in_bn && tid < FO) {
            for (int k = 0; k < FI; ++k) a = fmaf(shl[k], J.W[k * FO + tid], a);
        }
        J.bf[tid] = a;
    }
}

// ---------------- dense: H = in_tf(X) @ Wp + biasf ----------------
// 64 nodes per block, 256 threads; register-tiled 4 nodes x NT cols per
// thread. OUT_BN: accumulate relu stats of output into bnst.
template<int FI, int FO, int IN_BN, int IN_F32, int OUT_F32, int OUT_BN>
__global__ __launch_bounds__(256)
void k_dense(const void* __restrict__ Xv, const float* __restrict__ Wp,
             const float* __restrict__ biasf, void* __restrict__ Hv,
             float* __restrict__ bnst) {
    constexpr int NT  = (FO + 15) / 16;
    constexpr int FOP = 16 * NT;
    constexpr int FIP = FI + 2;
    constexpr int KP  = FI / 2;

    __shared__ __align__(16) float xs[64 * FIP];
    __shared__ float ls[96], lq[96];

    int tid = threadIdx.x;
    int node0 = blockIdx.x * 64;

    if (OUT_BN) {
        if (tid < 96) { ls[tid] = 0.0f; lq[tid] = 0.0f; }
    }

    // ---- stage X tile (coalesced) ----
    if (IN_F32) {
        for (int idx = tid; idx < 64 * FI; idx += 256) {
            int r = idx / FI, c = idx - r * FI;
            int n = node0 + r;
            float v = (n < NN) ? ((const float*)Xv)[(size_t)n * FI + c] : 0.0f;
            if (IN_BN) v = fmaxf(v, 0.0f);
            xs[r * FIP + c] = v;
        }
    } else {
        for (int idx = tid; idx < 64 * KP; idx += 256) {
            int r = idx / KP, c2 = idx - r * KP;
            int n = node0 + r;
            uint_t u = (n < NN) ? ((const uint_t*)Xv)[(size_t)n * KP + c2] : 0u;
            float f0 = bflo(u), f1 = bfhi(u);
            if (IN_BN) { f0 = fmaxf(f0, 0.0f); f1 = fmaxf(f1, 0.0f); }
            xs[r * FIP + 2 * c2]     = f0;
            xs[r * FIP + 2 * c2 + 1] = f1;
        }
    }
    __syncthreads();

    int ng = tid >> 4;
    int cg = tid & 15;

    float acc[4][NT];
    #pragma unroll
    for (int i = 0; i < 4; ++i)
        #pragma unroll
        for (int t = 0; t < NT; ++t) acc[i][t] = biasf[cg + 16 * t];

    #pragma unroll 2
    for (int k = 0; k < FI; k += 2) {
        float2 xv[4];
        #pragma unroll
        for (int i = 0; i < 4; ++i)
            xv[i] = *(const float2*)&xs[(ng + 16 * i) * FIP + k];
        const float* wrow = &Wp[(k >> 1) * 2 * FOP];
        #pragma unroll
        for (int t = 0; t < NT; ++t) {
            float2 w = *(const float2*)&wrow[2 * (cg + 16 * t)];
            #pragma unroll
            for (int i = 0; i < 4; ++i)
                acc[i][t] = fmaf(xv[i].y, w.y, fmaf(xv[i].x, w.x, acc[i][t]));
        }
    }

    if (OUT_BN) {
        #pragma unroll
        for (int t = 0; t < NT; ++t) {
            int j = cg + 16 * t;
            if (j < FO) {
                float ps = 0.0f, pq = 0.0f;
                #pragma unroll
                for (int i = 0; i < 4; ++i) {
                    if (node0 + ng + 16 * i < NN) {
                        float r = fmaxf(acc[i][t], 0.0f);
                        ps += r; pq += r * r;
                    }
                }
                atomicAdd(&ls[j], ps);
                atomicAdd(&lq[j], pq);
            }
        }
        __syncthreads();
        if (tid < FO) {
            atomicAdd(&bnst[tid], ls[tid]);
            atomicAdd(&bnst[96 + tid], lq[tid]);
        }
    }

    // ---- store (coalesced 16-lane segments) ----
    #pragma unroll
    for (int i = 0; i < 4; ++i) {
        int n = node0 + ng + 16 * i;
        if (n < NN) {
            #pragma unroll
            for (int t = 0; t < NT; ++t) {
                int j = cg + 16 * t;
                if (j < FO) {
                    if (OUT_F32) ((float*)Hv)[(size_t)n * FO + j] = acc[i][t];
                    else ((ushort_t*)Hv)[(size_t)n * FO + j] = packbf1(acc[i][t]);
                }
            }
        }
    }
}

// ---------------- CSR gather (bf16, 2 features/thread, packed cw) ----------------
// All edges processed in predicated 8-deep batches (no serial tail).
// OUT_BN: grid-strided (grid = 56*F2 so stride % F2 == 0 -> fixed j2/thread).
template<int FO, int IN_BN, int OUT_BIAS, int OUT_BN>
__global__ void k_gather(const ushort_t* __restrict__ h, const int* __restrict__ row_ptr,
                         const int2* __restrict__ cw, const float* __restrict__ dis,
                         const float* __restrict__ bnacc, const float* __restrict__ g,
                         const float* __restrict__ be,
                         const float* __restrict__ b, ushort_t* __restrict__ A,
                         float* __restrict__ bnacc_out) {
    constexpr int F2 = FO / 2;
    __shared__ float ls[96], lq[96];
    int tid = threadIdx.x;
    if (OUT_BN) {
        if (tid < 96) { ls[tid] = 0.0f; lq[tid] = 0.0f; }
        __syncthreads();
    }

    int t0 = blockIdx.x * blockDim.x + tid;
    const int stride = gridDim.x * blockDim.x;
    int j2 = t0 % F2;       // constant across strides (stride % F2 == 0 for OUT_BN)
    int j = 2 * j2;

    float sc0 = 1.0f, sh0 = 0.0f, sc1 = 1.0f, sh1 = 0.0f;
    if (IN_BN) {
        const float inv_n = 1.0f / NN;
        float mu0 = bnacc[j] * inv_n;
        float va0 = bnacc[96 + j] * inv_n - mu0 * mu0;
        float r0  = rsqrtf(va0 + 1e-5f);
        sc0 = g[j] * r0; sh0 = be[j] - mu0 * sc0;
        float mu1 = bnacc[j + 1] * inv_n;
        float va1 = bnacc[96 + j + 1] * inv_n - mu1 * mu1;
        float r1  = rsqrtf(va1 + 1e-5f);
        sc1 = g[j + 1] * r1; sh1 = be[j + 1] - mu1 * sc1;
    }

    const uint_t* h2 = (const uint_t*)h + j2;  // column pair j within rows
    float sx = 0.0f, qx = 0.0f, sy = 0.0f, qy = 0.0f;

    for (int t = t0; t < NN * F2; t += stride) {
        int i = t / F2;
        float di = dis[i];

        // self-loop
        uint_t su = h2[(size_t)i * F2];
        float vx = bflo(su), vy = bfhi(su);
        if (IN_BN) { vx = fmaxf(vx, 0.0f) * sc0 + sh0; vy = fmaxf(vy, 0.0f) * sc1 + sh1; }
        float ax = vx * di * di;
        float ay = vy * di * di;

        int beg = row_ptr[i], end = row_ptr[i + 1];
        // predicated 8-deep batches: every edge gets full MLP, no serial tail
        for (int k = beg; k < end; k += 8) {
            uint_t uu[8]; float ww[8];
            #pragma unroll
            for (int q = 0; q < 8; ++q) {
                int kq = k + q;
                int km = kq < end ? kq : end - 1;
                int2 c = cw[km];
                ww[q] = (kq < end) ? __int_as_float(c.y) : 0.0f;
                uu[q] = h2[(size_t)c.x * F2];
            }
            #pragma unroll
            for (int q = 0; q < 8; ++q) {
                float tx = bflo(uu[q]), ty = bfhi(uu[q]);
                if (IN_BN) { tx = fmaxf(tx, 0.0f) * sc0 + sh0; ty = fmaxf(ty, 0.0f) * sc1 + sh1; }
                ax = fmaf(tx, ww[q], ax); ay = fmaf(ty, ww[q], ay);
            }
        }
        if (OUT_BIAS) { ax += b[j]; ay += b[j + 1]; }
        if (OUT_BN) {
            float rx = fmaxf(ax, 0.0f), ry = fmaxf(ay, 0.0f);
            sx += rx; qx += rx * rx;
            sy += ry; qy += ry * ry;
        }
        ((uint_t*)A)[(size_t)i * F2 + j2] = packbf(ax, ay);
    }

    if (OUT_BN) {
        atomicAdd(&ls[j], sx);     atomicAdd(&ls[j + 1], sy);
        atomicAdd(&lq[j], qx);     atomicAdd(&lq[j + 1], qy);
        __syncthreads();
        if (tid < FO) {
            atomicAdd(&bnacc_out[tid], ls[tid]);
            atomicAdd(&bnacc_out[96 + tid], lq[tid]);
        }
    }
}

extern "C" void kernel_launch(void* const* d_in, const int* in_sizes, int n_in,
                              void* d_out, int out_size, void* d_ws, size_t ws_size,
                              hipStream_t stream) {
    const float* x = (const float*)d_in[0];
    const int* ei = (const int*)d_in[1];
    const int* src = ei;
    const int* dst = ei + NE;
    const float* W1 = (const float*)d_in[2];  const float* b1 = (const float*)d_in[3];
    const float* W2 = (const float*)d_in[4];  const float* b2 = (const float*)d_in[5];
    const float* W3 = (const float*)d_in[6];  const float* b3 = (const float*)d_in[7];
    const float* W4 = (const float*)d_in[8];  const float* b4 = (const float*)d_in[9];
    const float* W5 = (const float*)d_in[10]; const float* b5 = (const float*)d_in[11];
    const float* W6 = (const float*)d_in[12]; const float* b6 = (const float*)d_in[13];
    const float* g1 = (const float*)d_in[14]; const float* be1 = (const float*)d_in[15];
    const float* g2 = (const float*)d_in[16]; const float* be2 = (const float*)d_in[17];
    const float* g3 = (const float*)d_in[18]; const float* be3 = (const float*)d_in[19];
    const float* g4 = (const float*)d_in[20]; const float* be4 = (const float*)d_in[21];

    // workspace (~21.5 MB), cw first for 8B alignment
    int2* cw      = (int2*)d_ws;                 // NE
    float* dis    = (float*)(cw + NE);           // NN
    float* bnacc  = dis + NN;                    // 768
    float* Wp     = bnacc + 768;                 // 6*7040
    float* biasf  = Wp + 6 * 7040;               // 6*96
    int* deg      = (int*)(biasf + 6 * 96);      // NN
    int* row_ptr  = deg + NN;                    // NN+1
    int* cursor   = row_ptr + NN + 1;            // NN
    int* bsum     = cursor + NN;                 // 256
    int* boff     = bsum + 256;                  // 256
    ushort_t* hB  = (ushort_t*)(boff + 256);     // NN*70 bf16
    ushort_t* aB  = hB + (size_t)NN * 70;        // NN*70 bf16
    float* out    = (float*)d_out;

    const int NB = 256;
    const int DGRID = cdiv(NN, 64);
    float* bn0 = bnacc;        // L1 stats (g1,be1)
    float* bn1 = bnacc + 192;  // L2 stats (g2,be2)
    float* bn2 = bnacc + 384;  // L4 stats (g3,be3)
    float* bn3 = bnacc + 576;  // L5 stats (g4,be4)
    float* WpL[6]; float* bfL[6];
    for (int i = 0; i < 6; ++i) { WpL[i] = Wp + i * 7040; bfL[i] = biasf + i * 96; }

    // ---- CSR + normalization build ----
    k_prep<<<cdiv(NN, NB), NB, 0, stream>>>(deg, bnacc);
    k_hist<<<cdiv(NE, NB), NB, 0, stream>>>(dst, deg);
    k_bsum<<<NBLK, 256, 0, stream>>>(deg, bsum);
    k_bscan<<<1, 256, 0, stream>>>(bsum, boff, row_ptr);
    k_rowptr<<<NBLK, 256, 0, stream>>>(deg, boff, row_ptr, cursor, dis);
    k_fill<<<cdiv(NE, NB), NB, 0, stream>>>(src, dst, dis, cursor, cw);

    // ---- fold BN-independent layers (L1,L4,L5,L6) in one launch ----
    {
        FoldJobs js;
        js.j[0] = {W1, nullptr, nullptr, nullptr, nullptr, WpL[0], bfL[0], 88, 70, 0, 0};
        js.j[1] = {W4, b4,      nullptr, nullptr, nullptr, WpL[3], bfL[3], 50, 60, 0, 1};
        js.j[2] = {W5, b5,      nullptr, nullptr, nullptr, WpL[4], bfL[4], 60, 70, 0, 1};
        js.j[3] = {W6, b6,      nullptr, nullptr, nullptr, WpL[5], bfL[5], 70, 88, 0, 1};
        k_fold<<<4, 256, 0, stream>>>(js);
    }

    // ---- L1: dense x(88,f32)->hB(70); gather+bn0: hB -> aB + b1 ----
    k_dense<88, 70, 0, 1, 0, 0><<<DGRID, 256, 0, stream>>>(x, WpL[0], bfL[0], hB, nullptr);
    k_gather<70, 0, 1, 1><<<56 * 35, NB, 0, stream>>>(
        hB, row_ptr, cw, dis, nullptr, nullptr, nullptr, b1, aB, bn0);

    // ---- L2: fold(bn0); dense relu(aB)(70)->hB(60); gather+bn1 -> aB + b2 ----
    {
        FoldJobs js;
        js.j[0] = {W2, nullptr, bn0, g1, be1, WpL[1], bfL[1], 70, 60, 1, 0};
        k_fold<<<1, 256, 0, stream>>>(js);
    }
    k_dense<70, 60, 1, 0, 0, 0><<<DGRID, 256, 0, stream>>>(aB, WpL[1], bfL[1], hB, nullptr);
    k_gather<60, 0, 1, 1><<<56 * 30, NB, 0, stream>>>(
        hB, row_ptr, cw, dis, nullptr, nullptr, nullptr, b2, aB, bn1);

    // ---- L3: fold(bn1); dense relu(aB)(60)->hB(50); gather -> aB + b3 ----
    {
        FoldJobs js;
        js.j[0] = {W3, nullptr, bn1, g2, be2, WpL[2], bfL[2], 60, 50, 1, 0};
        k_fold<<<1, 256, 0, stream>>>(js);
    }
    k_dense<60, 50, 1, 0, 0, 0><<<DGRID, 256, 0, stream>>>(aB, WpL[2], bfL[2], hB, nullptr);
    k_gather<50, 0, 1, 0><<<cdiv((long long)NN * 25, NB), NB, 0, stream>>>(
        hB, row_ptr, cw, dis, nullptr, nullptr, nullptr, b3, aB, nullptr);

    // ---- L4 (aggregate-first): gather aB(A3)->hB(50); dense+bn2: hB->aB(60)+b4 ----
    k_gather<50, 0, 0, 0><<<cdiv((long long)NN * 25, NB), NB, 0, stream>>>(
        aB, row_ptr, cw, dis, nullptr, nullptr, nullptr, nullptr, hB, nullptr);
    k_dense<50, 60, 0, 0, 0, 1><<<DGRID, 256, 0, stream>>>(hB, WpL[3], bfL[3], aB, bn2);

    // ---- L5: gather bn2(relu(aB))->hB(60); dense+bn3: hB->aB(70)+b5 ----
    k_gather<60, 1, 0, 0><<<cdiv((long long)NN * 30, NB), NB, 0, stream>>>(
        aB, row_ptr, cw, dis, bn2, g3, be3, nullptr, hB, nullptr);
    k_dense<60, 70, 0, 0, 0, 1><<<DGRID, 256, 0, stream>>>(hB, WpL[4], bfL[4], aB, bn3);

    // ---- L6: gather bn3(relu(aB))->hB(70); dense: hB->out(88,f32)+b6 ----
    k_gather<70, 1, 0, 0><<<cdiv((long long)NN * 35, NB), NB, 0, stream>>>(
        aB, row_ptr, cw, dis, bn3, g4, be4, nullptr, hB, nullptr);
    k_dense<70, 88, 0, 0, 1, 0><<<DGRID, 256, 0, stream>>>(hB, WpL[5], bfL[5], out, nullptr);
}

// Round 12
// 553.185 us; speedup vs baseline: 1.1130x; 1.0911x over previous
//
#include <hip/hip_runtime.h>
#include <hip/hip_bf16.h>

typedef unsigned int  uint_t;
typedef unsigned short ushort_t;

#define NN 50000
#define NE 800000
#define NBLK 196   // cdiv(NN,256)

static inline int cdiv(long long a, long long b) { return (int)((a + b - 1) / b); }

// ---- bf16 pair helpers (element j at low 16 bits) ----
__device__ inline float bflo(uint_t u) { return __uint_as_float(u << 16); }
__device__ inline float bfhi(uint_t u) { return __uint_as_float(u & 0xffff0000u); }
__device__ inline uint_t packbf(float x, float y) {  // RNE
    uint_t xu = __float_as_uint(x), yu = __float_as_uint(y);
    xu += 0x7fffu + ((xu >> 16) & 1u);
    yu += 0x7fffu + ((yu >> 16) & 1u);
    return (xu >> 16) | (yu & 0xffff0000u);
}
__device__ inline ushort_t packbf1(float x) {
    uint_t xu = __float_as_uint(x);
    xu += 0x7fffu + ((xu >> 16) & 1u);
    return (ushort_t)(xu >> 16);
}

// ---------------- CSR build ----------------

__global__ void k_prep(int* __restrict__ deg, float* __restrict__ bnacc) {
    int i = blockIdx.x * blockDim.x + threadIdx.x;
    if (i < NN) deg[i] = 0;
    if (i < 768) bnacc[i] = 0.0f;
}

__global__ void k_hist(const int* __restrict__ dst, int* __restrict__ deg) {
    int e = blockIdx.x * blockDim.x + threadIdx.x;
    if (e < NE) {
        int d = dst[e];
        if ((unsigned)d < NN) atomicAdd(&deg[d], 1);
    }
}

__global__ void k_bsum(const int* __restrict__ deg, int* __restrict__ bsum) {
    __shared__ int l[256];
    int tid = threadIdx.x;
    int i = blockIdx.x * 256 + tid;
    l[tid] = (i < NN) ? deg[i] : 0;
    __syncthreads();
    for (int o = 128; o > 0; o >>= 1) {
        if (tid < o) l[tid] += l[tid + o];
        __syncthreads();
    }
    if (tid == 0) bsum[blockIdx.x] = l[0];
}

__global__ void k_bscan(const int* __restrict__ bsum, int* __restrict__ boff,
                        int* __restrict__ row_ptr) {
    __shared__ int l[256];
    int tid = threadIdx.x;
    int v = (tid < NBLK) ? bsum[tid] : 0;
    l[tid] = v;
    __syncthreads();
    for (int o = 1; o < 256; o <<= 1) {
        int t = (tid >= o) ? l[tid - o] : 0;
        __syncthreads();
        l[tid] += t;
        __syncthreads();
    }
    boff[tid] = l[tid] - v;
    if (tid == 255) row_ptr[NN] = l[255];
}

__global__ void k_rowptr(const int* __restrict__ deg, const int* __restrict__ boff,
                         int* __restrict__ row_ptr, int* __restrict__ cursor,
                         float* __restrict__ dis) {
    __shared__ int l[256];
    int tid = threadIdx.x;
    int i = blockIdx.x * 256 + tid;
    int v = (i < NN) ? deg[i] : 0;
    l[tid] = v;
    __syncthreads();
    for (int o = 1; o < 256; o <<= 1) {
        int t = (tid >= o) ? l[tid - o] : 0;
        __syncthreads();
        l[tid] += t;
        __syncthreads();
    }
    if (i < NN) {
        int excl = boff[blockIdx.x] + l[tid] - v;
        row_ptr[i] = excl;
        cursor[i] = excl;
        dis[i] = rsqrtf((float)(v + 1));  // +1 self-loop
    }
}

// packed (col, wgt) fill: ONE 8B random store per edge
__global__ void k_fill(const int* __restrict__ src, const int* __restrict__ dst,
                       const float* __restrict__ dis,
                       int* __restrict__ cursor, int2* __restrict__ cw) {
    int e = blockIdx.x * blockDim.x + threadIdx.x;
    if (e < NE) {
        int s = src[e], d = dst[e];
        if ((unsigned)s < NN && (unsigned)d < NN) {
            int p = atomicAdd(&cursor[d], 1);
            cw[p] = make_int2(s, __float_as_int(dis[s] * dis[d]));
        }
    }
}

// ---------------- generic weight fold/pad (runtime dims) ----------------
struct FoldJob {
    const float* W; const float* b;
    const float* bnacc; const float* g; const float* be;
    float* Wp; float* bf;
    int FI, FO, in_bn, out_b;
};
struct FoldJobs { FoldJob j[4]; };

__global__ void k_fold(FoldJobs jobs) {
    FoldJob J = jobs.j[blockIdx.x];
    const int FI = J.FI, FO = J.FO;
    const int NT = (FO + 15) / 16, FOP = 16 * NT;
    __shared__ float scl[96], shl[96];
    int tid = threadIdx.x;
    if (J.in_bn) {
        if (tid < FI) {
            const float inv_n = 1.0f / NN;
            float mu = J.bnacc[tid] * inv_n;
            float va = J.bnacc[96 + tid] * inv_n - mu * mu;
            float r  = rsqrtf(va + 1e-5f);
            float sc = J.g[tid] * r;
            scl[tid] = sc;
            shl[tid] = J.be[tid] - mu * sc;
        }
        __syncthreads();
    }
    for (int idx = tid; idx < FI * FOP; idx += 256) {
        int k = idx / FOP, j = idx - k * FOP;
        float w = (j < FO) ? J.W[k * FO + j] : 0.0f;
        if (J.in_bn) w *= scl[k];
        J.Wp[(k >> 1) * 2 * FOP + 2 * j + (k & 1)] = w;
    }
    if (tid < FOP) {
        float a = (J.out_b && tid < FO) ? J.b[tid] : 0.0f;
        if (J.in_bn && tid < FO) {
            for (int k = 0; k < FI; ++k) a = fmaf(shl[k], J.W[k * FO + tid], a);
        }
        J.bf[tid] = a;
    }
}

// ---------------- dense: H = in_tf(X) @ Wp + biasf ----------------
template<int FI, int FO, int IN_BN, int IN_F32, int OUT_F32, int OUT_BN>
__global__ __launch_bounds__(256)
void k_dense(const void* __restrict__ Xv, const float* __restrict__ Wp,
             const float* __restrict__ biasf, void* __restrict__ Hv,
             float* __restrict__ bnst) {
    constexpr int NT  = (FO + 15) / 16;
    constexpr int FOP = 16 * NT;
    constexpr int FIP = FI + 2;
    constexpr int KP  = FI / 2;

    __shared__ __align__(16) float xs[64 * FIP];
    __shared__ float ls[96], lq[96];

    int tid = threadIdx.x;
    int node0 = blockIdx.x * 64;

    if (OUT_BN) {
        if (tid < 96) { ls[tid] = 0.0f; lq[tid] = 0.0f; }
    }

    // ---- stage X tile (coalesced) ----
    if (IN_F32) {
        for (int idx = tid; idx < 64 * FI; idx += 256) {
            int r = idx / FI, c = idx - r * FI;
            int n = node0 + r;
            float v = (n < NN) ? ((const float*)Xv)[(size_t)n * FI + c] : 0.0f;
            if (IN_BN) v = fmaxf(v, 0.0f);
            xs[r * FIP + c] = v;
        }
    } else {
        for (int idx = tid; idx < 64 * KP; idx += 256) {
            int r = idx / KP, c2 = idx - r * KP;
            int n = node0 + r;
            uint_t u = (n < NN) ? ((const uint_t*)Xv)[(size_t)n * KP + c2] : 0u;
            float f0 = bflo(u), f1 = bfhi(u);
            if (IN_BN) { f0 = fmaxf(f0, 0.0f); f1 = fmaxf(f1, 0.0f); }
            xs[r * FIP + 2 * c2]     = f0;
            xs[r * FIP + 2 * c2 + 1] = f1;
        }
    }
    __syncthreads();

    int ng = tid >> 4;
    int cg = tid & 15;

    float acc[4][NT];
    #pragma unroll
    for (int i = 0; i < 4; ++i)
        #pragma unroll
        for (int t = 0; t < NT; ++t) acc[i][t] = biasf[cg + 16 * t];

    #pragma unroll 2
    for (int k = 0; k < FI; k += 2) {
        float2 xv[4];
        #pragma unroll
        for (int i = 0; i < 4; ++i)
            xv[i] = *(const float2*)&xs[(ng + 16 * i) * FIP + k];
        const float* wrow = &Wp[(k >> 1) * 2 * FOP];
        #pragma unroll
        for (int t = 0; t < NT; ++t) {
            float2 w = *(const float2*)&wrow[2 * (cg + 16 * t)];
            #pragma unroll
            for (int i = 0; i < 4; ++i)
                acc[i][t] = fmaf(xv[i].y, w.y, fmaf(xv[i].x, w.x, acc[i][t]));
        }
    }

    if (OUT_BN) {
        #pragma unroll
        for (int t = 0; t < NT; ++t) {
            int j = cg + 16 * t;
            if (j < FO) {
                float ps = 0.0f, pq = 0.0f;
                #pragma unroll
                for (int i = 0; i < 4; ++i) {
                    if (node0 + ng + 16 * i < NN) {
                        float r = fmaxf(acc[i][t], 0.0f);
                        ps += r; pq += r * r;
                    }
                }
                atomicAdd(&ls[j], ps);
                atomicAdd(&lq[j], pq);
            }
        }
        __syncthreads();
        if (tid < FO) {
            atomicAdd(&bnst[tid], ls[tid]);
            atomicAdd(&bnst[96 + tid], lq[tid]);
        }
    }

    // ---- store (coalesced 16-lane segments) ----
    #pragma unroll
    for (int i = 0; i < 4; ++i) {
        int n = node0 + ng + 16 * i;
        if (n < NN) {
            #pragma unroll
            for (int t = 0; t < NT; ++t) {
                int j = cg + 16 * t;
                if (j < FO) {
                    if (OUT_F32) ((float*)Hv)[(size_t)n * FO + j] = acc[i][t];
                    else ((ushort_t*)Hv)[(size_t)n * FO + j] = packbf1(acc[i][t]);
                }
            }
        }
    }
}

// ---------------- CSR gather (bf16, 2 features/thread, packed cw) ----------------
// Descending exact-batch ladder: 16 -> 8 -> 4 -> serial(<=3). No wasted loads,
// fewer dependent round-trips than fixed-8 + serial tail.
template<int FO, int IN_BN, int OUT_BIAS, int OUT_BN>
__global__ void k_gather(const ushort_t* __restrict__ h, const int* __restrict__ row_ptr,
                         const int2* __restrict__ cw, const float* __restrict__ dis,
                         const float* __restrict__ bnacc, const float* __restrict__ g,
                         const float* __restrict__ be,
                         const float* __restrict__ b, ushort_t* __restrict__ A,
                         float* __restrict__ bnacc_out) {
    constexpr int F2 = FO / 2;
    __shared__ float ls[96], lq[96];
    int tid = threadIdx.x;
    if (OUT_BN) {
        if (tid < 96) { ls[tid] = 0.0f; lq[tid] = 0.0f; }
        __syncthreads();
    }

    int t0 = blockIdx.x * blockDim.x + tid;
    const int stride = gridDim.x * blockDim.x;
    int j2 = t0 % F2;       // constant across strides (stride % F2 == 0 for OUT_BN)
    int j = 2 * j2;

    float sc0 = 1.0f, sh0 = 0.0f, sc1 = 1.0f, sh1 = 0.0f;
    if (IN_BN) {
        const float inv_n = 1.0f / NN;
        float mu0 = bnacc[j] * inv_n;
        float va0 = bnacc[96 + j] * inv_n - mu0 * mu0;
        float r0  = rsqrtf(va0 + 1e-5f);
        sc0 = g[j] * r0; sh0 = be[j] - mu0 * sc0;
        float mu1 = bnacc[j + 1] * inv_n;
        float va1 = bnacc[96 + j + 1] * inv_n - mu1 * mu1;
        float r1  = rsqrtf(va1 + 1e-5f);
        sc1 = g[j + 1] * r1; sh1 = be[j + 1] - mu1 * sc1;
    }

    const uint_t* h2 = (const uint_t*)h + j2;  // column pair j within rows
    float sx = 0.0f, qx = 0.0f, sy = 0.0f, qy = 0.0f;

    for (int t = t0; t < NN * F2; t += stride) {
        int i = t / F2;
        float di = dis[i];

        // self-loop
        uint_t su = h2[(size_t)i * F2];
        float vx = bflo(su), vy = bfhi(su);
        if (IN_BN) { vx = fmaxf(vx, 0.0f) * sc0 + sh0; vy = fmaxf(vy, 0.0f) * sc1 + sh1; }
        float ax = vx * di * di;
        float ay = vy * di * di;

        int k = row_ptr[i], end = row_ptr[i + 1];

        // 16-deep exact batches
        for (; k + 16 <= end; k += 16) {
            uint_t uu[16]; float ww[16];
            #pragma unroll
            for (int q = 0; q < 16; ++q) {
                int2 c = cw[k + q];
                ww[q] = __int_as_float(c.y);
                uu[q] = h2[(size_t)c.x * F2];
            }
            #pragma unroll
            for (int q = 0; q < 16; ++q) {
                float tx = bflo(uu[q]), ty = bfhi(uu[q]);
                if (IN_BN) { tx = fmaxf(tx, 0.0f) * sc0 + sh0; ty = fmaxf(ty, 0.0f) * sc1 + sh1; }
                ax = fmaf(tx, ww[q], ax); ay = fmaf(ty, ww[q], ay);
            }
        }
        // 8-deep
        for (; k + 8 <= end; k += 8) {
            uint_t uu[8]; float ww[8];
            #pragma unroll
            for (int q = 0; q < 8; ++q) {
                int2 c = cw[k + q];
                ww[q] = __int_as_float(c.y);
                uu[q] = h2[(size_t)c.x * F2];
            }
            #pragma unroll
            for (int q = 0; q < 8; ++q) {
                float tx = bflo(uu[q]), ty = bfhi(uu[q]);
                if (IN_BN) { tx = fmaxf(tx, 0.0f) * sc0 + sh0; ty = fmaxf(ty, 0.0f) * sc1 + sh1; }
                ax = fmaf(tx, ww[q], ax); ay = fmaf(ty, ww[q], ay);
            }
        }
        // 4-deep
        for (; k + 4 <= end; k += 4) {
            uint_t uu[4]; float ww[4];
            #pragma unroll
            for (int q = 0; q < 4; ++q) {
                int2 c = cw[k + q];
                ww[q] = __int_as_float(c.y);
                uu[q] = h2[(size_t)c.x * F2];
            }
            #pragma unroll
            for (int q = 0; q < 4; ++q) {
                float tx = bflo(uu[q]), ty = bfhi(uu[q]);
                if (IN_BN) { tx = fmaxf(tx, 0.0f) * sc0 + sh0; ty = fmaxf(ty, 0.0f) * sc1 + sh1; }
                ax = fmaf(tx, ww[q], ax); ay = fmaf(ty, ww[q], ay);
            }
        }
        // serial remainder (<=3)
        for (; k < end; ++k) {
            int2 c = cw[k];
            float w = __int_as_float(c.y);
            uint_t u = h2[(size_t)c.x * F2];
            float tx = bflo(u), ty = bfhi(u);
            if (IN_BN) { tx = fmaxf(tx, 0.0f) * sc0 + sh0; ty = fmaxf(ty, 0.0f) * sc1 + sh1; }
            ax = fmaf(tx, w, ax); ay = fmaf(ty, w, ay);
        }

        if (OUT_BIAS) { ax += b[j]; ay += b[j + 1]; }
        if (OUT_BN) {
            float rx = fmaxf(ax, 0.0f), ry = fmaxf(ay, 0.0f);
            sx += rx; qx += rx * rx;
            sy += ry; qy += ry * ry;
        }
        ((uint_t*)A)[(size_t)i * F2 + j2] = packbf(ax, ay);
    }

    if (OUT_BN) {
        atomicAdd(&ls[j], sx);     atomicAdd(&ls[j + 1], sy);
        atomicAdd(&lq[j], qx);     atomicAdd(&lq[j + 1], qy);
        __syncthreads();
        if (tid < FO) {
            atomicAdd(&bnacc_out[tid], ls[tid]);
            atomicAdd(&bnacc_out[96 + tid], lq[tid]);
        }
    }
}

extern "C" void kernel_launch(void* const* d_in, const int* in_sizes, int n_in,
                              void* d_out, int out_size, void* d_ws, size_t ws_size,
                              hipStream_t stream) {
    const float* x = (const float*)d_in[0];
    const int* ei = (const int*)d_in[1];
    const int* src = ei;
    const int* dst = ei + NE;
    const float* W1 = (const float*)d_in[2];  const float* b1 = (const float*)d_in[3];
    const float* W2 = (const float*)d_in[4];  const float* b2 = (const float*)d_in[5];
    const float* W3 = (const float*)d_in[6];  const float* b3 = (const float*)d_in[7];
    const float* W4 = (const float*)d_in[8];  const float* b4 = (const float*)d_in[9];
    const float* W5 = (const float*)d_in[10]; const float* b5 = (const float*)d_in[11];
    const float* W6 = (const float*)d_in[12]; const float* b6 = (const float*)d_in[13];
    const float* g1 = (const float*)d_in[14]; const float* be1 = (const float*)d_in[15];
    const float* g2 = (const float*)d_in[16]; const float* be2 = (const float*)d_in[17];
    const float* g3 = (const float*)d_in[18]; const float* be3 = (const float*)d_in[19];
    const float* g4 = (const float*)d_in[20]; const float* be4 = (const float*)d_in[21];

    // workspace (~21.5 MB), cw first for 8B alignment
    int2* cw      = (int2*)d_ws;                 // NE
    float* dis    = (float*)(cw + NE);           // NN
    float* bnacc  = dis + NN;                    // 768
    float* Wp     = bnacc + 768;                 // 6*7040
    float* biasf  = Wp + 6 * 7040;               // 6*96
    int* deg      = (int*)(biasf + 6 * 96);      // NN
    int* row_ptr  = deg + NN;                    // NN+1
    int* cursor   = row_ptr + NN + 1;            // NN
    int* bsum     = cursor + NN;                 // 256
    int* boff     = bsum + 256;                  // 256
    ushort_t* hB  = (ushort_t*)(boff + 256);     // NN*70 bf16
    ushort_t* aB  = hB + (size_t)NN * 70;        // NN*70 bf16
    float* out    = (float*)d_out;

    const int NB = 256;
    const int DGRID = cdiv(NN, 64);
    float* bn0 = bnacc;        // L1 stats (g1,be1)
    float* bn1 = bnacc + 192;  // L2 stats (g2,be2)
    float* bn2 = bnacc + 384;  // L4 stats (g3,be3)
    float* bn3 = bnacc + 576;  // L5 stats (g4,be4)
    float* WpL[6]; float* bfL[6];
    for (int i = 0; i < 6; ++i) { WpL[i] = Wp + i * 7040; bfL[i] = biasf + i * 96; }

    // ---- CSR + normalization build ----
    k_prep<<<cdiv(NN, NB), NB, 0, stream>>>(deg, bnacc);
    k_hist<<<cdiv(NE, NB), NB, 0, stream>>>(dst, deg);
    k_bsum<<<NBLK, 256, 0, stream>>>(deg, bsum);
    k_bscan<<<1, 256, 0, stream>>>(bsum, boff, row_ptr);
    k_rowptr<<<NBLK, 256, 0, stream>>>(deg, boff, row_ptr, cursor, dis);
    k_fill<<<cdiv(NE, NB), NB, 0, stream>>>(src, dst, dis, cursor, cw);

    // ---- fold BN-independent layers (L1,L4,L5,L6) in one launch ----
    {
        FoldJobs js;
        js.j[0] = {W1, nullptr, nullptr, nullptr, nullptr, WpL[0], bfL[0], 88, 70, 0, 0};
        js.j[1] = {W4, b4,      nullptr, nullptr, nullptr, WpL[3], bfL[3], 50, 60, 0, 1};
        js.j[2] = {W5, b5,      nullptr, nullptr, nullptr, WpL[4], bfL[4], 60, 70, 0, 1};
        js.j[3] = {W6, b6,      nullptr, nullptr, nullptr, WpL[5], bfL[5], 70, 88, 0, 1};
        k_fold<<<4, 256, 0, stream>>>(js);
    }

    // ---- L1: dense x(88,f32)->hB(70); gather+bn0: hB -> aB + b1 ----
    k_dense<88, 70, 0, 1, 0, 0><<<DGRID, 256, 0, stream>>>(x, WpL[0], bfL[0], hB, nullptr);
    k_gather<70, 0, 1, 1><<<56 * 35, NB, 0, stream>>>(
        hB, row_ptr, cw, dis, nullptr, nullptr, nullptr, b1, aB, bn0);

    // ---- L2: fold(bn0); dense relu(aB)(70)->hB(60); gather+bn1 -> aB + b2 ----
    {
        FoldJobs js;
        js.j[0] = {W2, nullptr, bn0, g1, be1, WpL[1], bfL[1], 70, 60, 1, 0};
        k_fold<<<1, 256, 0, stream>>>(js);
    }
    k_dense<70, 60, 1, 0, 0, 0><<<DGRID, 256, 0, stream>>>(aB, WpL[1], bfL[1], hB, nullptr);
    k_gather<60, 0, 1, 1><<<56 * 30, NB, 0, stream>>>(
        hB, row_ptr, cw, dis, nullptr, nullptr, nullptr, b2, aB, bn1);

    // ---- L3: fold(bn1); dense relu(aB)(60)->hB(50); gather -> aB + b3 ----
    {
        FoldJobs js;
        js.j[0] = {W3, nullptr, bn1, g2, be2, WpL[2], bfL[2], 60, 50, 1, 0};
        k_fold<<<1, 256, 0, stream>>>(js);
    }
    k_dense<60, 50, 1, 0, 0, 0><<<DGRID, 256, 0, stream>>>(aB, WpL[2], bfL[2], hB, nullptr);
    k_gather<50, 0, 1, 0><<<cdiv((long long)NN * 25, NB), NB, 0, stream>>>(
        hB, row_ptr, cw, dis, nullptr, nullptr, nullptr, b3, aB, nullptr);

    // ---- L4 (aggregate-first): gather aB(A3)->hB(50); dense+bn2: hB->aB(60)+b4 ----
    k_gather<50, 0, 0, 0><<<cdiv((long long)NN * 25, NB), NB, 0, stream>>>(
        aB, row_ptr, cw, dis, nullptr, nullptr, nullptr, nullptr, hB, nullptr);
    k_dense<50, 60, 0, 0, 0, 1><<<DGRID, 256, 0, stream>>>(hB, WpL[3], bfL[3], aB, bn2);

    // ---- L5: gather bn2(relu(aB))->hB(60); dense+bn3: hB->aB(70)+b5 ----
    k_gather<60, 1, 0, 0><<<cdiv((long long)NN * 30, NB), NB, 0, stream>>>(
        aB, row_ptr, cw, dis, bn2, g3, be3, nullptr, hB, nullptr);
    k_dense<60, 70, 0, 0, 0, 1><<<DGRID, 256, 0, stream>>>(hB, WpL[4], bfL[4], aB, bn3);

    // ---- L6: gather bn3(relu(aB))->hB(70); dense: hB->out(88,f32)+b6 ----
    k_gather<70, 1, 0, 0><<<cdiv((long long)NN * 35, NB), NB, 0, stream>>>(
        aB, row_ptr, cw, dis, bn3, g4, be4, nullptr, hB, nullptr);
    k_dense<70, 88, 0, 0, 1, 0><<<DGRID, 256, 0, stream>>>(hB, WpL[5], bfL[5], out, nullptr);
}